// Round 1
// baseline (94.062 us; speedup 1.0000x reference)
//
#include <hip/hip_runtime.h>

// CRPS loss: preds [B=8, N=16, C=4, H=128, W=256] f32, gt [8,4,128,256] f32 -> scalar f32
// out = mean_over_points( sum_n |p_n - g|/N  -  sum_{i<j} |p_i - p_j| / (N*(N-1)) )
// N=16 -> term1 scale 1/16, term2 scale 1/240.

#define CHW      131072            // C*H*W = 4*128*256
#define CHW4     32768             // CHW/4 (float4 units)
#define NENS     16
#define BATCH    8
#define NPOINTS  (BATCH * CHW)     // 1,048,576 spatial points
#define NP4      (NPOINTS / 4)     // 262,144 float4 points
#define BLOCK    256
#define GRID1    (NP4 / BLOCK)     // 1024 blocks

__global__ __launch_bounds__(BLOCK) void crps_partial_kernel(
    const float4* __restrict__ preds,   // [B, N, CHW/4] in float4 units
    const float4* __restrict__ gt,      // [B, CHW/4]
    float* __restrict__ partial)        // [GRID1]
{
    const int t  = blockIdx.x * BLOCK + threadIdx.x;  // float4 point id over [B, CHW/4]
    const int b  = t >> 15;                            // / CHW4
    const int s4 = t & (CHW4 - 1);

    const float4* pbase = preds + ((b * NENS) << 15) + s4;
    const float4 g = gt[t];

    float4 p[NENS];
#pragma unroll
    for (int n = 0; n < NENS; ++n)
        p[n] = pbase[n << 15];   // stride CHW4 float4 between ensemble members

    float a1 = 0.0f;  // sum |p_i - g|
    float a2 = 0.0f;  // sum_{i<j} |p_i - p_j|
#pragma unroll
    for (int i = 0; i < NENS; ++i) {
        a1 += fabsf(p[i].x - g.x) + fabsf(p[i].y - g.y)
            + fabsf(p[i].z - g.z) + fabsf(p[i].w - g.w);
#pragma unroll
        for (int j = i + 1; j < NENS; ++j) {
            a2 += fabsf(p[i].x - p[j].x) + fabsf(p[i].y - p[j].y)
                + fabsf(p[i].z - p[j].z) + fabsf(p[i].w - p[j].w);
        }
    }
    float local = a1 * (1.0f / 16.0f) - a2 * (1.0f / 240.0f);

    // wave (64-lane) shuffle reduction
#pragma unroll
    for (int off = 32; off > 0; off >>= 1)
        local += __shfl_down(local, off, 64);

    __shared__ float smem[BLOCK / 64];
    const int lane = threadIdx.x & 63;
    const int wid  = threadIdx.x >> 6;
    if (lane == 0) smem[wid] = local;
    __syncthreads();
    if (threadIdx.x == 0) {
        float s = 0.0f;
#pragma unroll
        for (int w = 0; w < BLOCK / 64; ++w) s += smem[w];
        partial[blockIdx.x] = s;
    }
}

__global__ __launch_bounds__(BLOCK) void crps_final_kernel(
    const float* __restrict__ partial, float* __restrict__ out)
{
    float local = 0.0f;
    for (int i = threadIdx.x; i < GRID1; i += BLOCK)
        local += partial[i];
#pragma unroll
    for (int off = 32; off > 0; off >>= 1)
        local += __shfl_down(local, off, 64);

    __shared__ float smem[BLOCK / 64];
    const int lane = threadIdx.x & 63;
    const int wid  = threadIdx.x >> 6;
    if (lane == 0) smem[wid] = local;
    __syncthreads();
    if (threadIdx.x == 0) {
        float s = 0.0f;
#pragma unroll
        for (int w = 0; w < BLOCK / 64; ++w) s += smem[w];
        out[0] = s * (1.0f / (float)NPOINTS);
    }
}

extern "C" void kernel_launch(void* const* d_in, const int* in_sizes, int n_in,
                              void* d_out, int out_size, void* d_ws, size_t ws_size,
                              hipStream_t stream) {
    const float4* preds = (const float4*)d_in[0];
    const float4* gt    = (const float4*)d_in[1];
    float* partial      = (float*)d_ws;     // GRID1 floats = 4 KiB scratch
    float* out          = (float*)d_out;

    crps_partial_kernel<<<GRID1, BLOCK, 0, stream>>>(preds, gt, partial);
    crps_final_kernel<<<1, BLOCK, 0, stream>>>(partial, out);
}